// Round 4
// baseline (217.681 us; speedup 1.0000x reference)
//
#include <hip/hip_runtime.h>
#include <math.h>

// Shapes (fixed): Na=32, La=32, B=64, Lb=32, Din=H=768.

typedef __attribute__((ext_vector_type(8))) short bfrag8;   // 8 bf16 in 4 VGPRs
typedef __attribute__((ext_vector_type(4))) float f32x4;

__device__ __forceinline__ unsigned short f2bf(float x) {
  union { float f; unsigned u; } v; v.f = x;
  unsigned r = v.u + 0x7fffu + ((v.u >> 16) & 1u);
  return (unsigned short)(r >> 16);
}
__device__ __forceinline__ float bf2f(unsigned short u) {
  union { unsigned u; float f; } v; v.u = ((unsigned)u) << 16; return v.f;
}

// ---------------- merged: f32->bf16 casts (3 tensors) + 4 weight transposes ----------------
__global__ __launch_bounds__(256) void prep_kernel(
    const float* __restrict__ a0, const float* __restrict__ a1, const float* __restrict__ a2,
    unsigned short* __restrict__ o0, unsigned short* __restrict__ o1, unsigned short* __restrict__ o2,
    const float* __restrict__ W0, const float* __restrict__ W1,
    const float* __restrict__ W2, const float* __restrict__ W3,
    unsigned short* __restrict__ T0, unsigned short* __restrict__ T1,
    unsigned short* __restrict__ T2, unsigned short* __restrict__ T3) {
  __shared__ float t[32][33];
  int bx = blockIdx.x;
  if (bx < 2328) {  // cast path
    const float* in; unsigned short* out; int i, n4;
    if (bx < 768)       { in = a0; out = o0; i = bx * 256 + threadIdx.x;          n4 = 196608; }
    else if (bx < 2304) { in = a1; out = o1; i = (bx - 768) * 256 + threadIdx.x;  n4 = 393216; }
    else                { in = a2; out = o2; i = (bx - 2304) * 256 + threadIdx.x; n4 = 6144; }
    if (i >= n4) return;
    float4 f = ((const float4*)in)[i];
    ushort4 o;
    o.x = f2bf(f.x); o.y = f2bf(f.y); o.z = f2bf(f.z); o.w = f2bf(f.w);
    ((ushort4*)out)[i] = o;
    return;
  }
  // transpose path
  int idx = bx - 2328;
  int z = idx / 576, r2 = idx % 576;
  int tby = r2 / 24, tbx = r2 % 24;
  const float* W = (z == 0) ? W0 : (z == 1) ? W1 : (z == 2) ? W2 : W3;
  unsigned short* O = (z == 0) ? T0 : (z == 1) ? T1 : (z == 2) ? T2 : T3;
  const int gx = tbx * 32, gy = tby * 32;
  const int tx = threadIdx.x & 31, ty = threadIdx.x >> 5;
#pragma unroll
  for (int u = 0; u < 4; ++u) {
    int row = ty + u * 8;
    t[row][tx] = W[(size_t)(gy + row) * 768 + gx + tx];
  }
  __syncthreads();
#pragma unroll
  for (int u = 0; u < 4; ++u) {
    int row = ty + u * 8;
    O[(size_t)(gx + row) * 768 + gy + tx] = f2bf(t[tx][row]);
  }
}

// ---------------- merged projection GEMMs: z=0:q->qb+qT, 1:k->kb, 2:v->vT, 3:ecls(f32) --------
__global__ __launch_bounds__(256) void proj_gemm_kernel(
    const unsigned short* __restrict__ Ae, const unsigned short* __restrict__ Am,
    const unsigned short* __restrict__ Acls,
    const unsigned short* __restrict__ WqT, const unsigned short* __restrict__ WkT,
    const unsigned short* __restrict__ WvT, const unsigned short* __restrict__ WclsT,
    const float* __restrict__ bq, const float* __restrict__ bk,
    const float* __restrict__ bv, const float* __restrict__ bcls,
    unsigned short* __restrict__ qb, unsigned short* __restrict__ qT,
    unsigned short* __restrict__ kb, unsigned short* __restrict__ vT,
    float* __restrict__ ecls) {
  const int z = blockIdx.z;
  const int M = (z == 0) ? 1024 : (z == 3) ? 32 : 2048;
  const int bm = blockIdx.y * 128;
  if (bm >= M) return;
  const unsigned short* A = (z == 3) ? Acls : (z == 0) ? Ae : Am;
  const unsigned short* B = (z == 0) ? WqT : (z == 1) ? WkT : (z == 2) ? WvT : WclsT;
  const float* bias = (z == 0) ? bq : (z == 1) ? bk : (z == 2) ? bv : bcls;

  __shared__ unsigned short As[128 * 64];
  __shared__ unsigned short Bs[128 * 64];
  const int t = threadIdx.x;
  const int bn = blockIdx.x * 128;
  const int l = t & 63, w = t >> 6;
  const int wm = w & 1, wn = w >> 1;

  f32x4 acc[4][4];
#pragma unroll
  for (int mi = 0; mi < 4; ++mi)
#pragma unroll
    for (int nj = 0; nj < 4; ++nj) { f32x4 zz = {0.f, 0.f, 0.f, 0.f}; acc[mi][nj] = zz; }

  for (int k0 = 0; k0 < 768; k0 += 64) {
    __syncthreads();
#pragma unroll
    for (int u = 0; u < 4; ++u) {
      int c = t + u * 256;
      int row = c >> 3, kc = c & 7;
      int gm = bm + row; gm = gm < M ? gm : M - 1;
      int4 av = *(const int4*)(A + (size_t)gm * 768 + k0 + kc * 8);
      *(int4*)(As + row * 64 + ((kc ^ (row & 7)) * 8)) = av;
      int4 bv4 = *(const int4*)(B + (size_t)(bn + row) * 768 + k0 + kc * 8);
      *(int4*)(Bs + row * 64 + ((kc ^ (row & 7)) * 8)) = bv4;
    }
    __syncthreads();
#pragma unroll
    for (int kk = 0; kk < 2; ++kk) {
      bfrag8 af[4], bf[4];
      const int kc = kk * 4 + (l >> 4);
#pragma unroll
      for (int mi = 0; mi < 4; ++mi) {
        int arow = wm * 64 + mi * 16 + (l & 15);
        af[mi] = *(const bfrag8*)(As + arow * 64 + ((kc ^ (arow & 7)) * 8));
      }
#pragma unroll
      for (int nj = 0; nj < 4; ++nj) {
        int brow = wn * 64 + nj * 16 + (l & 15);
        bf[nj] = *(const bfrag8*)(Bs + brow * 64 + ((kc ^ (brow & 7)) * 8));
      }
#pragma unroll
      for (int mi = 0; mi < 4; ++mi)
#pragma unroll
        for (int nj = 0; nj < 4; ++nj)
          acc[mi][nj] = __builtin_amdgcn_mfma_f32_16x16x32_bf16(af[mi], bf[nj], acc[mi][nj], 0, 0, 0);
    }
  }

  const int col = l & 15, rq = l >> 4;
#pragma unroll
  for (int mi = 0; mi < 4; ++mi) {
#pragma unroll
    for (int nj = 0; nj < 4; ++nj) {
      int gn = bn + wn * 64 + nj * 16 + col;
      float bs = bias[gn];
#pragma unroll
      for (int r = 0; r < 4; ++r) {
        int gm = bm + wm * 64 + mi * 16 + rq * 4 + r;
        if (gm >= M) continue;
        float val = acc[mi][nj][r] + bs;
        unsigned short bfv = f2bf(val);
        if (z == 0) {
          qb[(size_t)gm * 768 + gn] = bfv;
          int at = gm >> 5, j = gm & 31;
          qT[((size_t)at * 768 + gn) * 32 + j] = bfv;
        } else if (z == 1) kb[(size_t)gm * 768 + gn] = bfv;
        else if (z == 2) {
          int bb = gm >> 5, j = gm & 31;
          vT[((size_t)bb * 768 + gn) * 32 + j] = bfv;
        } else ecls[(size_t)gm * 768 + gn] = val;
      }
    }
  }
}

// ---------------- inverse L2 row norms from bf16 ----------------
__global__ __launch_bounds__(256) void rownorm_bf16_kernel(
    const unsigned short* __restrict__ qb, const unsigned short* __restrict__ kb,
    float* __restrict__ iq, float* __restrict__ ik) {
  int row = blockIdx.x * 4 + (threadIdx.x >> 6);
  int lane = threadIdx.x & 63;
  const unsigned short* src; float* dst;
  if (row < 1024) { src = qb + (size_t)row * 768; dst = iq + row; }
  else            { src = kb + (size_t)(row - 1024) * 768; dst = ik + (row - 1024); }
  const unsigned short* p = src + lane * 12;
  float s = 0.f;
#pragma unroll
  for (int u = 0; u < 3; ++u) {
    ushort4 u4 = *(const ushort4*)(p + u * 4);
    float x0 = bf2f(u4.x), x1 = bf2f(u4.y), x2 = bf2f(u4.z), x3 = bf2f(u4.w);
    s += x0 * x0 + x1 * x1 + x2 * x2 + x3 * x3;
  }
#pragma unroll
  for (int m = 1; m < 64; m <<= 1) s += __shfl_xor(s, m);
  if (lane == 0) *dst = 1.0f / fmaxf(sqrtf(s), 1e-8f);
}

// ---------------- cosine GEMM: C[1024][2048] = (qb @ kb^T) * iq * ik ----------------
__global__ __launch_bounds__(256) void cos_mfma_kernel(
    const unsigned short* __restrict__ A, const unsigned short* __restrict__ B,
    const float* __restrict__ iq, const float* __restrict__ ik, float* __restrict__ C) {
  __shared__ unsigned short As[128 * 64];
  __shared__ unsigned short Bs[128 * 64];
  const int t = threadIdx.x;
  const int bn = blockIdx.x * 128, bm = blockIdx.y * 128;
  const int l = t & 63, w = t >> 6;
  const int wm = w & 1, wn = w >> 1;

  f32x4 acc[4][4];
#pragma unroll
  for (int mi = 0; mi < 4; ++mi)
#pragma unroll
    for (int nj = 0; nj < 4; ++nj) { f32x4 zz = {0.f, 0.f, 0.f, 0.f}; acc[mi][nj] = zz; }

  for (int k0 = 0; k0 < 768; k0 += 64) {
    __syncthreads();
#pragma unroll
    for (int u = 0; u < 4; ++u) {
      int c = t + u * 256;
      int row = c >> 3, kc = c & 7;
      int4 av = *(const int4*)(A + (size_t)(bm + row) * 768 + k0 + kc * 8);
      *(int4*)(As + row * 64 + ((kc ^ (row & 7)) * 8)) = av;
      int4 bv4 = *(const int4*)(B + (size_t)(bn + row) * 768 + k0 + kc * 8);
      *(int4*)(Bs + row * 64 + ((kc ^ (row & 7)) * 8)) = bv4;
    }
    __syncthreads();
#pragma unroll
    for (int kk = 0; kk < 2; ++kk) {
      bfrag8 af[4], bf[4];
      const int kc = kk * 4 + (l >> 4);
#pragma unroll
      for (int mi = 0; mi < 4; ++mi) {
        int arow = wm * 64 + mi * 16 + (l & 15);
        af[mi] = *(const bfrag8*)(As + arow * 64 + ((kc ^ (arow & 7)) * 8));
      }
#pragma unroll
      for (int nj = 0; nj < 4; ++nj) {
        int brow = wn * 64 + nj * 16 + (l & 15);
        bf[nj] = *(const bfrag8*)(Bs + brow * 64 + ((kc ^ (brow & 7)) * 8));
      }
#pragma unroll
      for (int mi = 0; mi < 4; ++mi)
#pragma unroll
        for (int nj = 0; nj < 4; ++nj)
          acc[mi][nj] = __builtin_amdgcn_mfma_f32_16x16x32_bf16(af[mi], bf[nj], acc[mi][nj], 0, 0, 0);
    }
  }

  const int col = l & 15, rq = l >> 4;
#pragma unroll
  for (int mi = 0; mi < 4; ++mi) {
#pragma unroll
    for (int nj = 0; nj < 4; ++nj) {
      int gn = bn + wn * 64 + nj * 16 + col;
      float kn = ik[gn];
#pragma unroll
      for (int r = 0; r < 4; ++r) {
        int gm = bm + wm * 64 + mi * 16 + rq * 4 + r;
        C[(size_t)gm * 2048 + gn] = acc[mi][nj][r] * iq[gm] * kn;
      }
    }
  }
}

// ---------------- Mega-fused: sinkhorn -> attended=[T|I]@[v;q] -> LN1 -> softpool -> LN2 -> score
// One 256-thread block per (b,a) pair.
__global__ __launch_bounds__(256) void attn_fused_kernel(
    const float* __restrict__ C,            // [1024][2048] raw cosine
    const unsigned short* __restrict__ vT,  // [64][768][32]: vT[b][h][j] = v[b*32+j][h]
    const unsigned short* __restrict__ qT,  // [32][768][32]: qT[a][h][j] = q[a*32+j][h]
    const float* __restrict__ ecls,
    const float* __restrict__ entity_cls, const float* __restrict__ mention_cls,
    const float* __restrict__ ln1_g, const float* __restrict__ ln1_b,
    const float* __restrict__ Wsp, const float* __restrict__ bsp,
    const float* __restrict__ ln2_g, const float* __restrict__ ln2_b,
    float* __restrict__ out) {
  const int pair = blockIdx.x;
  const int b = pair >> 5, a = pair & 31;
  const int t = threadIdx.x;
  const int w = t >> 6, l = t & 63;
  const int cg = l & 15, rq = l >> 4;

  // Ts_bf: 32 rows x 32 cols bf16, XOR-swizzled in 8-short chunks (16B-aligned frag reads)
  __shared__ unsigned short Ts_bf[32 * 32];
  __shared__ float redA[4][32], redB[4][32];   // redA doubles as sinkhorn colpart
  __shared__ float svals[32];
  __shared__ float red2[4][2];
  __shared__ float red3[4];

  // ================= Sinkhorn (registers + shuffles) =================
  {
    const int si = t >> 3, sj = (t & 7) << 2;
    const float* base = C + (size_t)(a * 32 + si) * 2048 + b * 32 + sj;
    float4 c4 = *(const float4*)base;
    float qv[4] = { expf(c4.x * 10.f), expf(c4.y * 10.f), expf(c4.z * 10.f), expf(c4.w * 10.f) };
    for (int it = 0; it < 10; ++it) {
      float rs = qv[0] + qv[1] + qv[2] + qv[3];
      rs += __shfl_xor(rs, 1); rs += __shfl_xor(rs, 2); rs += __shfl_xor(rs, 4);
      float rinv = __builtin_amdgcn_rcpf(rs);
#pragma unroll
      for (int u = 0; u < 4; ++u) qv[u] *= rinv;
      float cp[4] = { qv[0], qv[1], qv[2], qv[3] };
#pragma unroll
      for (int m = 8; m < 64; m <<= 1) {
#pragma unroll
        for (int u = 0; u < 4; ++u) cp[u] += __shfl_xor(cp[u], m);
      }
      __syncthreads();
      if (l < 8) {
#pragma unroll
        for (int u = 0; u < 4; ++u) redA[w][sj + u] = cp[u];
      }
      __syncthreads();
#pragma unroll
      for (int u = 0; u < 4; ++u) {
        float cs = redA[0][sj + u] + redA[1][sj + u] + redA[2][sj + u] + redA[3][sj + u];
        qv[u] *= __builtin_amdgcn_rcpf(cs);
      }
    }
    float ss = qv[0] * qv[0] + qv[1] * qv[1] + qv[2] * qv[2] + qv[3] * qv[3];
    ss += __shfl_xor(ss, 1); ss += __shfl_xor(ss, 2); ss += __shfl_xor(ss, 4);
    float tinv = rsqrtf(fmaxf(ss, 1e-24f));
    // write bf16 into swizzled A-tile: chunk = sj>>3, within = sj&7
    ushort4 o;
    o.x = f2bf(qv[0] * tinv); o.y = f2bf(qv[1] * tinv);
    o.z = f2bf(qv[2] * tinv); o.w = f2bf(qv[3] * tinv);
    int chunk = sj >> 3, within = sj & 7;
    *(ushort4*)(Ts_bf + si * 32 + ((chunk ^ (si & 3)) * 8) + within) = o;
  }
  __syncthreads();

  // ================= A fragments: T rows + identity =================
  bfrag8 af[2], afI[2];
#pragma unroll
  for (int mi = 0; mi < 2; ++mi) {
    int row = mi * 16 + cg;
    af[mi] = *(const bfrag8*)(Ts_bf + row * 32 + ((rq ^ (row & 3)) * 8));
    bfrag8 fI;
#pragma unroll
    for (int u = 0; u < 8; ++u) fI[u] = (row == rq * 8 + u) ? (short)0x3F80 : (short)0;
    afI[mi] = fI;
  }

  // ================= MFMA: attended = T@v + I@q =================
  f32x4 acc[2][12];
  const unsigned short* vTb = vT + (size_t)b * 768 * 32;
  const unsigned short* qTa = qT + (size_t)a * 768 * 32;
#pragma unroll
  for (int nj = 0; nj < 12; ++nj) {
    int h = w * 192 + nj * 16 + cg;
    bfrag8 vf = *(const bfrag8*)(vTb + (size_t)h * 32 + rq * 8);
    bfrag8 qf = *(const bfrag8*)(qTa + (size_t)h * 32 + rq * 8);
#pragma unroll
    for (int mi = 0; mi < 2; ++mi) {
      f32x4 zz = {0.f, 0.f, 0.f, 0.f};
      f32x4 p = __builtin_amdgcn_mfma_f32_16x16x32_bf16(af[mi], vf, zz, 0, 0, 0);
      acc[mi][nj] = __builtin_amdgcn_mfma_f32_16x16x32_bf16(afI[mi], qf, p, 0, 0, 0);
    }
  }

  // ================= LN1 stats per attended row =================
  float s1[2][4], s2[2][4];
#pragma unroll
  for (int mi = 0; mi < 2; ++mi)
#pragma unroll
    for (int r = 0; r < 4; ++r) {
      float s = 0.f, q2 = 0.f;
#pragma unroll
      for (int nj = 0; nj < 12; ++nj) { float x = acc[mi][nj][r]; s += x; q2 += x * x; }
      s1[mi][r] = s; s2[mi][r] = q2;
    }
#pragma unroll
  for (int m = 1; m < 16; m <<= 1) {
#pragma unroll
    for (int mi = 0; mi < 2; ++mi)
#pragma unroll
      for (int r = 0; r < 4; ++r) {
        s1[mi][r] += __shfl_xor(s1[mi][r], m);
        s2[mi][r] += __shfl_xor(s2[mi][r], m);
      }
  }
  __syncthreads();        // sinkhorn colpart readers done before redA rewrite
  if (cg == 0) {
#pragma unroll
    for (int mi = 0; mi < 2; ++mi)
#pragma unroll
      for (int r = 0; r < 4; ++r) {
        int row = mi * 16 + rq * 4 + r;
        redA[w][row] = s1[mi][r]; redB[w][row] = s2[mi][r];
      }
  }
  __syncthreads();
  float mean[2][4], rstd[2][4];
#pragma unroll
  for (int mi = 0; mi < 2; ++mi)
#pragma unroll
    for (int r = 0; r < 4; ++r) {
      int row = mi * 16 + rq * 4 + r;
      float s = redA[0][row] + redA[1][row] + redA[2][row] + redA[3][row];
      float q2 = redB[0][row] + redB[1][row] + redB[2][row] + redB[3][row];
      float m1 = s * (1.0f / 768.0f);
      float var = q2 * (1.0f / 768.0f) - m1 * m1;
      mean[mi][r] = m1; rstd[mi][r] = rsqrtf(var + 1e-5f);
    }

  // ================= apply LN1 + softpool logits =================
  float sp[2][4] = {};
#pragma unroll
  for (int nj = 0; nj < 12; ++nj) {
    int h = w * 192 + nj * 16 + cg;
    float g1 = ln1_g[h], b1 = ln1_b[h], wsp = Wsp[h];
#pragma unroll
    for (int mi = 0; mi < 2; ++mi)
#pragma unroll
      for (int r = 0; r < 4; ++r) {
        float x = (acc[mi][nj][r] - mean[mi][r]) * rstd[mi][r] * g1 + b1;
        acc[mi][nj][r] = x;
        sp[mi][r] += x * wsp;
      }
  }
#pragma unroll
  for (int m = 1; m < 16; m <<= 1) {
#pragma unroll
    for (int mi = 0; mi < 2; ++mi)
#pragma unroll
      for (int r = 0; r < 4; ++r) sp[mi][r] += __shfl_xor(sp[mi][r], m);
  }
  __syncthreads();
  if (cg == 0) {
#pragma unroll
    for (int mi = 0; mi < 2; ++mi)
#pragma unroll
      for (int r = 0; r < 4; ++r) redA[w][mi * 16 + rq * 4 + r] = sp[mi][r];
  }
  __syncthreads();
  // lane-parallel softmax over 32 logits -> normalized weights in svals
  if (t < 32) {
    float x = redA[0][t] + redA[1][t] + redA[2][t] + redA[3][t] + bsp[0];
    float mx = x;
#pragma unroll
    for (int m = 1; m < 32; m <<= 1) mx = fmaxf(mx, __shfl_xor(mx, m));
    float e = expf(x - mx);
    float se = e;
#pragma unroll
    for (int m = 1; m < 32; m <<= 1) se += __shfl_xor(se, m);
    svals[t] = e * __builtin_amdgcn_rcpf(se);
  }
  __syncthreads();
  float wv[2][4];
#pragma unroll
  for (int mi = 0; mi < 2; ++mi)
#pragma unroll
    for (int r = 0; r < 4; ++r) wv[mi][r] = svals[mi * 16 + rq * 4 + r];

  // ================= pooled + LN2 + scores =================
  float pol[12];
#pragma unroll
  for (int nj = 0; nj < 12; ++nj) {
    float s = 0.f;
#pragma unroll
    for (int mi = 0; mi < 2; ++mi)
#pragma unroll
      for (int r = 0; r < 4; ++r) s += wv[mi][r] * acc[mi][nj][r];
    pol[nj] = s;
  }
#pragma unroll
  for (int nj = 0; nj < 12; ++nj) {
    pol[nj] += __shfl_xor(pol[nj], 16);
    pol[nj] += __shfl_xor(pol[nj], 32);
  }
  float ps = 0.f, pq = 0.f;
#pragma unroll
  for (int nj = 0; nj < 12; ++nj) { ps += pol[nj]; pq += pol[nj] * pol[nj]; }
#pragma unroll
  for (int m = 1; m < 64; m <<= 1) { ps += __shfl_xor(ps, m); pq += __shfl_xor(pq, m); }
  if (l == 0) { red2[w][0] = ps; red2[w][1] = pq; }
  __syncthreads();
  {
    float s = red2[0][0] + red2[1][0] + red2[2][0] + red2[3][0];
    float q2 = red2[0][1] + red2[1][1] + red2[2][1] + red2[3][1];
    const float inv = 1.0f / (4.0f * 768.0f);   // x4 rq replication
    float m2 = s * inv;
    float var2 = q2 * inv - m2 * m2;
    float rs2 = rsqrtf(var2 + 1e-5f);

    const float* ea = entity_cls + (size_t)a * 768;
    const float* mb = mention_cls + (size_t)b * 768;
    const float* ec = ecls + (size_t)a * 768;
    float tot = 0.f;
#pragma unroll
    for (int nj = 0; nj < 12; ++nj) {
      int h = w * 192 + nj * 16 + cg;
      float ctx = (pol[nj] - m2) * rs2 * ln2_g[h] + ln2_b[h];
      tot += ctx * ec[h] + mb[h] * ea[h];
    }
#pragma unroll
    for (int m = 1; m < 64; m <<= 1) tot += __shfl_xor(tot, m);
    if (l == 0) red3[w] = tot;
  }
  __syncthreads();
  if (t == 0) {
    float g = red3[0] + red3[1] + red3[2] + red3[3];
    out[b * 32 + a] = 0.5f * 0.25f * g;
  }
}

extern "C" void kernel_launch(void* const* d_in, const int* in_sizes, int n_in,
                              void* d_out, int out_size, void* d_ws, size_t ws_size,
                              hipStream_t stream) {
  const float* entity_cls     = (const float*)d_in[0];
  const float* entity_tokens  = (const float*)d_in[1];
  const float* mention_cls    = (const float*)d_in[2];
  const float* mention_tokens = (const float*)d_in[3];
  const float* Wq = (const float*)d_in[4];   const float* bq = (const float*)d_in[5];
  const float* Wk = (const float*)d_in[6];   const float* bk = (const float*)d_in[7];
  const float* Wv = (const float*)d_in[8];   const float* bv = (const float*)d_in[9];
  const float* ln1_g = (const float*)d_in[10]; const float* ln1_b = (const float*)d_in[11];
  const float* Wcls = (const float*)d_in[12];  const float* bcls = (const float*)d_in[13];
  const float* Wsp = (const float*)d_in[14];   const float* bsp = (const float*)d_in[15];
  const float* ln2_g = (const float*)d_in[16]; const float* ln2_b = (const float*)d_in[17];
  float* out = (float*)d_out;

  // workspace layout
  float* ws   = (float*)d_ws;
  float* ecls = ws;                          // 32*768
  float* iq   = ecls + 24576;                // 1024
  float* ik   = iq + 1024;                   // 2048
  unsigned short* qb = (unsigned short*)(ik + 2048);  // 1024*768
  unsigned short* qT = qb + 786432;                   // 32*768*32
  unsigned short* kb = qT + 786432;                   // 2048*768
  unsigned short* vT = kb + 1572864;                  // 64*768*32
  char* R = (char*)(vT + 1572864);
  unsigned short* Ae    = (unsigned short*)R;         // staging, aliased later by C
  unsigned short* Am    = Ae + 786432;
  unsigned short* Acls  = Am + 1572864;
  unsigned short* WqT   = Acls + 24576;
  unsigned short* WkT   = WqT + 589824;
  unsigned short* WvT   = WkT + 589824;
  unsigned short* WclsT = WvT + 589824;
  float* C = (float*)R;                               // 1024*2048 f32

  dim3 blk(256);
  prep_kernel<<<dim3(4632), blk, 0, stream>>>(
      entity_tokens, mention_tokens, entity_cls, Ae, Am, Acls,
      Wq, Wk, Wv, Wcls, WqT, WkT, WvT, WclsT);
  proj_gemm_kernel<<<dim3(6, 16, 4), blk, 0, stream>>>(
      Ae, Am, Acls, WqT, WkT, WvT, WclsT, bq, bk, bv, bcls, qb, qT, kb, vT, ecls);
  rownorm_bf16_kernel<<<dim3(768), blk, 0, stream>>>(qb, kb, iq, ik);
  cos_mfma_kernel<<<dim3(16, 8), blk, 0, stream>>>(qb, kb, iq, ik, C);
  attn_fused_kernel<<<dim3(2048), blk, 0, stream>>>(
      C, vT, qT, ecls, entity_cls, mention_cls,
      ln1_g, ln1_b, Wsp, bsp, ln2_g, ln2_b, out);
}

// Round 5
// 208.088 us; speedup vs baseline: 1.0461x; 1.0461x over previous
//
#include <hip/hip_runtime.h>
#include <math.h>

// Shapes (fixed): Na=32, La=32, B=64, Lb=32, Din=H=768.

typedef __attribute__((ext_vector_type(8))) short bfrag8;   // 8 bf16 in 4 VGPRs
typedef __attribute__((ext_vector_type(4))) float f32x4;

__device__ __forceinline__ unsigned short f2bf(float x) {
  union { float f; unsigned u; } v; v.f = x;
  unsigned r = v.u + 0x7fffu + ((v.u >> 16) & 1u);
  return (unsigned short)(r >> 16);
}
__device__ __forceinline__ float bf2f(unsigned short u) {
  union { unsigned u; float f; } v; v.u = ((unsigned)u) << 16; return v.f;
}

// ---------------- prep: casts (3 tensors) + zero norm buffer + 4 weight transposes -------------
__global__ __launch_bounds__(256) void prep_kernel(
    const float* __restrict__ a0, const float* __restrict__ a1, const float* __restrict__ a2,
    unsigned short* __restrict__ o0, unsigned short* __restrict__ o1, unsigned short* __restrict__ o2,
    float* __restrict__ nrm,   // iq_sq[1024] + ik_sq[2048] contiguous, zeroed here
    const float* __restrict__ W0, const float* __restrict__ W1,
    const float* __restrict__ W2, const float* __restrict__ W3,
    unsigned short* __restrict__ T0, unsigned short* __restrict__ T1,
    unsigned short* __restrict__ T2, unsigned short* __restrict__ T3) {
  __shared__ float t[32][33];
  int bx = blockIdx.x;
  if (bx < 2331) {
    if (bx < 2328) {  // cast path
      const float* in; unsigned short* out; int i, n4;
      if (bx < 768)       { in = a0; out = o0; i = bx * 256 + threadIdx.x;          n4 = 196608; }
      else if (bx < 2304) { in = a1; out = o1; i = (bx - 768) * 256 + threadIdx.x;  n4 = 393216; }
      else                { in = a2; out = o2; i = (bx - 2304) * 256 + threadIdx.x; n4 = 6144; }
      if (i >= n4) return;
      float4 f = ((const float4*)in)[i];
      ushort4 o;
      o.x = f2bf(f.x); o.y = f2bf(f.y); o.z = f2bf(f.z); o.w = f2bf(f.w);
      ((ushort4*)out)[i] = o;
    } else {          // zero norm buffer (3072 floats = 768 float4)
      int i = (bx - 2328) * 256 + threadIdx.x;
      if (i < 768) ((float4*)nrm)[i] = make_float4(0.f, 0.f, 0.f, 0.f);
    }
    return;
  }
  // transpose path
  int idx = bx - 2331;
  int z = idx / 576, r2 = idx % 576;
  int tby = r2 / 24, tbx = r2 % 24;
  const float* W = (z == 0) ? W0 : (z == 1) ? W1 : (z == 2) ? W2 : W3;
  unsigned short* O = (z == 0) ? T0 : (z == 1) ? T1 : (z == 2) ? T2 : T3;
  const int gx = tbx * 32, gy = tby * 32;
  const int tx = threadIdx.x & 31, ty = threadIdx.x >> 5;
#pragma unroll
  for (int u = 0; u < 4; ++u) {
    int row = ty + u * 8;
    t[row][tx] = W[(size_t)(gy + row) * 768 + gx + tx];
  }
  __syncthreads();
#pragma unroll
  for (int u = 0; u < 4; ++u) {
    int row = ty + u * 8;
    O[(size_t)(gx + row) * 768 + gy + tx] = f2bf(t[tx][row]);
  }
}

// ---------------- projections: z=0:q->qb+qT(+iq_sq), 1:k->kb(+ik_sq), 2:v->vT, 3:ecls ---------
__global__ __launch_bounds__(256) void proj_gemm_kernel(
    const unsigned short* __restrict__ Ae, const unsigned short* __restrict__ Am,
    const unsigned short* __restrict__ Acls,
    const unsigned short* __restrict__ WqT, const unsigned short* __restrict__ WkT,
    const unsigned short* __restrict__ WvT, const unsigned short* __restrict__ WclsT,
    const float* __restrict__ bq, const float* __restrict__ bk,
    const float* __restrict__ bv, const float* __restrict__ bcls,
    unsigned short* __restrict__ qb, unsigned short* __restrict__ qT,
    unsigned short* __restrict__ kb, unsigned short* __restrict__ vT,
    float* __restrict__ ecls, float* __restrict__ iq_sq, float* __restrict__ ik_sq) {
  const int z = blockIdx.z;
  const int M = (z == 0) ? 1024 : (z == 3) ? 32 : 2048;
  const int bm = blockIdx.y * 128;
  if (bm >= M) return;
  const unsigned short* A = (z == 3) ? Acls : (z == 0) ? Ae : Am;
  const unsigned short* B = (z == 0) ? WqT : (z == 1) ? WkT : (z == 2) ? WvT : WclsT;
  const float* bias = (z == 0) ? bq : (z == 1) ? bk : (z == 2) ? bv : bcls;

  __shared__ unsigned short As[128 * 64];
  __shared__ unsigned short Bs[128 * 64];
  const int t = threadIdx.x;
  const int bn = blockIdx.x * 128;
  const int l = t & 63, w = t >> 6;
  const int wm = w & 1, wn = w >> 1;

  f32x4 acc[4][4];
#pragma unroll
  for (int mi = 0; mi < 4; ++mi)
#pragma unroll
    for (int nj = 0; nj < 4; ++nj) { f32x4 zz = {0.f, 0.f, 0.f, 0.f}; acc[mi][nj] = zz; }

  for (int k0 = 0; k0 < 768; k0 += 64) {
    __syncthreads();
#pragma unroll
    for (int u = 0; u < 4; ++u) {
      int c = t + u * 256;
      int row = c >> 3, kc = c & 7;
      int gm = bm + row; gm = gm < M ? gm : M - 1;
      int4 av = *(const int4*)(A + (size_t)gm * 768 + k0 + kc * 8);
      *(int4*)(As + row * 64 + ((kc ^ (row & 7)) * 8)) = av;
      int4 bv4 = *(const int4*)(B + (size_t)(bn + row) * 768 + k0 + kc * 8);
      *(int4*)(Bs + row * 64 + ((kc ^ (row & 7)) * 8)) = bv4;
    }
    __syncthreads();
#pragma unroll
    for (int kk = 0; kk < 2; ++kk) {
      bfrag8 af[4], bf[4];
      const int kc = kk * 4 + (l >> 4);
#pragma unroll
      for (int mi = 0; mi < 4; ++mi) {
        int arow = wm * 64 + mi * 16 + (l & 15);
        af[mi] = *(const bfrag8*)(As + arow * 64 + ((kc ^ (arow & 7)) * 8));
      }
#pragma unroll
      for (int nj = 0; nj < 4; ++nj) {
        int brow = wn * 64 + nj * 16 + (l & 15);
        bf[nj] = *(const bfrag8*)(Bs + brow * 64 + ((kc ^ (brow & 7)) * 8));
      }
#pragma unroll
      for (int mi = 0; mi < 4; ++mi)
#pragma unroll
        for (int nj = 0; nj < 4; ++nj)
          acc[mi][nj] = __builtin_amdgcn_mfma_f32_16x16x32_bf16(af[mi], bf[nj], acc[mi][nj], 0, 0, 0);
    }
  }

  const int col = l & 15, rq = l >> 4;
  float p[4][4] = {};   // per-row sumsq partial (z<2)
#pragma unroll
  for (int mi = 0; mi < 4; ++mi) {
#pragma unroll
    for (int nj = 0; nj < 4; ++nj) {
      int gn = bn + wn * 64 + nj * 16 + col;
      float bs = bias[gn];
#pragma unroll
      for (int r = 0; r < 4; ++r) {
        int gm = bm + wm * 64 + mi * 16 + rq * 4 + r;
        if (gm >= M) continue;
        float val = acc[mi][nj][r] + bs;
        if (z < 2) p[mi][r] += val * val;
        unsigned short bfv = f2bf(val);
        if (z == 0) {
          qb[(size_t)gm * 768 + gn] = bfv;
          int at = gm >> 5, j = gm & 31;
          qT[((size_t)at * 768 + gn) * 32 + j] = bfv;
        } else if (z == 1) kb[(size_t)gm * 768 + gn] = bfv;
        else if (z == 2) {
          int bb = gm >> 5, j = gm & 31;
          vT[((size_t)bb * 768 + gn) * 32 + j] = bfv;
        } else ecls[(size_t)gm * 768 + gn] = val;
      }
    }
  }
  if (z < 2) {
    float* nrm = (z == 0) ? iq_sq : ik_sq;
#pragma unroll
    for (int mi = 0; mi < 4; ++mi)
#pragma unroll
      for (int r = 0; r < 4; ++r) {
        float s = p[mi][r];
        s += __shfl_xor(s, 1); s += __shfl_xor(s, 2);
        s += __shfl_xor(s, 4); s += __shfl_xor(s, 8);
        if (col == 0) {
          int gm = bm + wm * 64 + mi * 16 + rq * 4 + r;
          atomicAdd(&nrm[gm], s);
        }
      }
  }
}

// ---------------- cosine GEMM + in-register Sinkhorn + row L2-norm -> bf16 T tiles ------------
// block tile 128(m:q-rows) x 64(n:k-rows); wave = 64 rows x 32 cols = two 32x32 (a,b) tiles,
// held entirely in C/D accumulators. Sinkhorn reductions are pure reg-adds + shuffles.
__global__ __launch_bounds__(256) void cos_sink_kernel(
    const unsigned short* __restrict__ qb, const unsigned short* __restrict__ kb,
    const float* __restrict__ iq_sq, const float* __restrict__ ik_sq,
    unsigned short* __restrict__ Tg) {   // [64b*32a][32][32] bf16
  __shared__ unsigned short As[128 * 64];
  __shared__ unsigned short Bs[64 * 64];
  __shared__ float ldsIq[128], ldsIk[64];
  const int t = threadIdx.x;
  const int bn = blockIdx.x * 64, bm = blockIdx.y * 128;
  const int l = t & 63, w = t >> 6;
  const int wm = w & 1, wn = w >> 1;
  const int cg = l & 15, rq = l >> 4;

  if (t < 128) ldsIq[t] = iq_sq[bm + t];
  else if (t < 192) ldsIk[t - 128] = ik_sq[bn + t - 128];

  f32x4 acc[4][2];
#pragma unroll
  for (int mi = 0; mi < 4; ++mi)
#pragma unroll
    for (int nj = 0; nj < 2; ++nj) { f32x4 zz = {0.f, 0.f, 0.f, 0.f}; acc[mi][nj] = zz; }

  for (int k0 = 0; k0 < 768; k0 += 64) {
    __syncthreads();
#pragma unroll
    for (int u = 0; u < 4; ++u) {
      int c = t + u * 256;
      int row = c >> 3, kc = c & 7;
      int4 av = *(const int4*)(qb + (size_t)(bm + row) * 768 + k0 + kc * 8);
      *(int4*)(As + row * 64 + ((kc ^ (row & 7)) * 8)) = av;
    }
#pragma unroll
    for (int u = 0; u < 2; ++u) {
      int c = t + u * 256;
      int row = c >> 3, kc = c & 7;
      int4 bv4 = *(const int4*)(kb + (size_t)(bn + row) * 768 + k0 + kc * 8);
      *(int4*)(Bs + row * 64 + ((kc ^ (row & 7)) * 8)) = bv4;
    }
    __syncthreads();
#pragma unroll
    for (int kk = 0; kk < 2; ++kk) {
      bfrag8 af[4], bf[2];
      const int kc = kk * 4 + rq;
#pragma unroll
      for (int mi = 0; mi < 4; ++mi) {
        int arow = wm * 64 + mi * 16 + cg;
        af[mi] = *(const bfrag8*)(As + arow * 64 + ((kc ^ (arow & 7)) * 8));
      }
#pragma unroll
      for (int nj = 0; nj < 2; ++nj) {
        int brow = wn * 32 + nj * 16 + cg;
        bf[nj] = *(const bfrag8*)(Bs + brow * 64 + ((kc ^ (brow & 7)) * 8));
      }
#pragma unroll
      for (int mi = 0; mi < 4; ++mi)
#pragma unroll
        for (int nj = 0; nj < 2; ++nj)
          acc[mi][nj] = __builtin_amdgcn_mfma_f32_16x16x32_bf16(af[mi], bf[nj], acc[mi][nj], 0, 0, 0);
    }
  }

  // ---- cosine scale + exp(10*cos) ----
  float irow[4][4], icol[2];
#pragma unroll
  for (int mi = 0; mi < 4; ++mi)
#pragma unroll
    for (int r = 0; r < 4; ++r) {
      float s = ldsIq[wm * 64 + mi * 16 + rq * 4 + r];
      irow[mi][r] = 1.0f / fmaxf(sqrtf(s), 1e-8f);
    }
#pragma unroll
  for (int nj = 0; nj < 2; ++nj) {
    float s = ldsIk[wn * 32 + nj * 16 + cg];
    icol[nj] = 1.0f / fmaxf(sqrtf(s), 1e-8f);
  }
#pragma unroll
  for (int mi = 0; mi < 4; ++mi)
#pragma unroll
    for (int nj = 0; nj < 2; ++nj)
#pragma unroll
      for (int r = 0; r < 4; ++r)
        acc[mi][nj][r] = __expf(acc[mi][nj][r] * irow[mi][r] * icol[nj] * 10.0f);

  // ---- 10 Sinkhorn iterations, barrier-free (two independent 32x32 tiles per wave) ----
  for (int it = 0; it < 10; ++it) {
#pragma unroll
    for (int mi = 0; mi < 4; ++mi)
#pragma unroll
      for (int r = 0; r < 4; ++r) {
        float rs = acc[mi][0][r] + acc[mi][1][r];
        rs += __shfl_xor(rs, 1); rs += __shfl_xor(rs, 2);
        rs += __shfl_xor(rs, 4); rs += __shfl_xor(rs, 8);
        float rinv = __builtin_amdgcn_rcpf(rs);
        acc[mi][0][r] *= rinv; acc[mi][1][r] *= rinv;
      }
#pragma unroll
    for (int ta = 0; ta < 2; ++ta)
#pragma unroll
      for (int nj = 0; nj < 2; ++nj) {
        float cs = acc[2 * ta][nj][0] + acc[2 * ta][nj][1] + acc[2 * ta][nj][2] + acc[2 * ta][nj][3]
                 + acc[2 * ta + 1][nj][0] + acc[2 * ta + 1][nj][1] + acc[2 * ta + 1][nj][2] + acc[2 * ta + 1][nj][3];
        cs += __shfl_xor(cs, 16); cs += __shfl_xor(cs, 32);
        float cinv = __builtin_amdgcn_rcpf(cs);
#pragma unroll
        for (int mi2 = 0; mi2 < 2; ++mi2)
#pragma unroll
          for (int r = 0; r < 4; ++r) acc[2 * ta + mi2][nj][r] *= cinv;
      }
  }

  // ---- final row L2 normalize ----
#pragma unroll
  for (int mi = 0; mi < 4; ++mi)
#pragma unroll
    for (int r = 0; r < 4; ++r) {
      float ss = acc[mi][0][r] * acc[mi][0][r] + acc[mi][1][r] * acc[mi][1][r];
      ss += __shfl_xor(ss, 1); ss += __shfl_xor(ss, 2);
      ss += __shfl_xor(ss, 4); ss += __shfl_xor(ss, 8);
      float tinv = 1.0f / fmaxf(sqrtf(ss), 1e-12f);
      acc[mi][0][r] *= tinv; acc[mi][1][r] *= tinv;
    }

  // ---- store bf16 tiles: Tg[(b*32+a)*1024 + i*32 + j] ----
  const int b_idx = (bn >> 5) + wn;
#pragma unroll
  for (int mi = 0; mi < 4; ++mi) {
    const int a_idx = (bm >> 5) + wm * 2 + (mi >> 1);
    unsigned short* base = Tg + (((size_t)b_idx * 32 + a_idx) << 10);
    const int ri0 = (mi & 1) * 16 + rq * 4;
#pragma unroll
    for (int nj = 0; nj < 2; ++nj)
#pragma unroll
      for (int r = 0; r < 4; ++r)
        base[(ri0 + r) * 32 + nj * 16 + cg] = f2bf(acc[mi][nj][r]);
  }
}

// ---------------- attn: attended=[T|I]@[v;q] -> LN1 -> softpool -> LN2 -> scores --------------
__global__ __launch_bounds__(256) void attn_kernel(
    const unsigned short* __restrict__ Tg,  // [2048][32][32] bf16 tiles
    const unsigned short* __restrict__ vT,  // [64][768][32]
    const unsigned short* __restrict__ qT,  // [32][768][32]
    const float* __restrict__ ecls,
    const float* __restrict__ entity_cls, const float* __restrict__ mention_cls,
    const float* __restrict__ ln1_g, const float* __restrict__ ln1_b,
    const float* __restrict__ Wsp, const float* __restrict__ bsp,
    const float* __restrict__ ln2_g, const float* __restrict__ ln2_b,
    float* __restrict__ out) {
  const int pair = blockIdx.x;
  const int b = pair >> 5, a = pair & 31;
  const int t = threadIdx.x;
  const int w = t >> 6, l = t & 63;
  const int cg = l & 15, rq = l >> 4;

  __shared__ unsigned short Ts_bf[32 * 32];
  __shared__ float redA[4][32], redB[4][32];
  __shared__ float svals[32];
  __shared__ float red2[4][2];
  __shared__ float red3[4];

  if (t < 128) {  // stage T tile into swizzled LDS (16B per thread)
    int i = t >> 2, c = t & 3;
    int4 v4 = *(const int4*)(Tg + ((size_t)pair << 10) + i * 32 + c * 8);
    *(int4*)(Ts_bf + i * 32 + ((c ^ (i & 3)) * 8)) = v4;
  }
  __syncthreads();

  bfrag8 af[2], afI[2];
#pragma unroll
  for (int mi = 0; mi < 2; ++mi) {
    int row = mi * 16 + cg;
    af[mi] = *(const bfrag8*)(Ts_bf + row * 32 + ((rq ^ (row & 3)) * 8));
    bfrag8 fI;
#pragma unroll
    for (int u = 0; u < 8; ++u) fI[u] = (row == rq * 8 + u) ? (short)0x3F80 : (short)0;
    afI[mi] = fI;
  }

  f32x4 acc[2][12];
  const unsigned short* vTb = vT + (size_t)b * 768 * 32;
  const unsigned short* qTa = qT + (size_t)a * 768 * 32;
#pragma unroll
  for (int nj = 0; nj < 12; ++nj) {
    int h = w * 192 + nj * 16 + cg;
    bfrag8 vf = *(const bfrag8*)(vTb + (size_t)h * 32 + rq * 8);
    bfrag8 qf = *(const bfrag8*)(qTa + (size_t)h * 32 + rq * 8);
#pragma unroll
    for (int mi = 0; mi < 2; ++mi) {
      f32x4 zz = {0.f, 0.f, 0.f, 0.f};
      f32x4 p = __builtin_amdgcn_mfma_f32_16x16x32_bf16(af[mi], vf, zz, 0, 0, 0);
      acc[mi][nj] = __builtin_amdgcn_mfma_f32_16x16x32_bf16(afI[mi], qf, p, 0, 0, 0);
    }
  }

  // ---- LN1 stats ----
  float s1[2][4], s2[2][4];
#pragma unroll
  for (int mi = 0; mi < 2; ++mi)
#pragma unroll
    for (int r = 0; r < 4; ++r) {
      float s = 0.f, q2 = 0.f;
#pragma unroll
      for (int nj = 0; nj < 12; ++nj) { float x = acc[mi][nj][r]; s += x; q2 += x * x; }
      s1[mi][r] = s; s2[mi][r] = q2;
    }
#pragma unroll
  for (int m = 1; m < 16; m <<= 1) {
#pragma unroll
    for (int mi = 0; mi < 2; ++mi)
#pragma unroll
      for (int r = 0; r < 4; ++r) {
        s1[mi][r] += __shfl_xor(s1[mi][r], m);
        s2[mi][r] += __shfl_xor(s2[mi][r], m);
      }
  }
  if (cg == 0) {
#pragma unroll
    for (int mi = 0; mi < 2; ++mi)
#pragma unroll
      for (int r = 0; r < 4; ++r) {
        int row = mi * 16 + rq * 4 + r;
        redA[w][row] = s1[mi][r]; redB[w][row] = s2[mi][r];
      }
  }
  __syncthreads();
  float mean[2][4], rstd[2][4];
#pragma unroll
  for (int mi = 0; mi < 2; ++mi)
#pragma unroll
    for (int r = 0; r < 4; ++r) {
      int row = mi * 16 + rq * 4 + r;
      float s = redA[0][row] + redA[1][row] + redA[2][row] + redA[3][row];
      float q2 = redB[0][row] + redB[1][row] + redB[2][row] + redB[3][row];
      float m1 = s * (1.0f / 768.0f);
      float var = q2 * (1.0f / 768.0f) - m1 * m1;
      mean[mi][r] = m1; rstd[mi][r] = rsqrtf(var + 1e-5f);
    }

  // ---- apply LN1 + softpool logits ----
  float sp[2][4] = {};
#pragma unroll
  for (int nj = 0; nj < 12; ++nj) {
    int h = w * 192 + nj * 16 + cg;
    float g1 = ln1_g[h], b1 = ln1_b[h], wsp = Wsp[h];
#pragma unroll
    for (int mi = 0; mi < 2; ++mi)
#pragma unroll
      for (int r = 0; r < 4; ++r) {
        float x = (acc[mi][nj][r] - mean[mi][r]) * rstd[mi][r] * g1 + b1;
        acc[mi][nj][r] = x;
        sp[mi][r] += x * wsp;
      }
  }
#pragma unroll
  for (int m = 1; m < 16; m <<= 1) {
#pragma unroll
    for (int mi = 0; mi < 2; ++mi)
#pragma unroll
      for (int r = 0; r < 4; ++r) sp[mi][r] += __shfl_xor(sp[mi][r], m);
  }
  __syncthreads();
  if (cg == 0) {
#pragma unroll
    for (int mi = 0; mi < 2; ++mi)
#pragma unroll
      for (int r = 0; r < 4; ++r) redA[w][mi * 16 + rq * 4 + r] = sp[mi][r];
  }
  __syncthreads();
  if (t < 32) {  // lane-parallel softmax
    float x = redA[0][t] + redA[1][t] + redA[2][t] + redA[3][t] + bsp[0];
    float mx = x;
#pragma unroll
    for (int m = 1; m < 32; m <<= 1) mx = fmaxf(mx, __shfl_xor(mx, m));
    float e = expf(x - mx);
    float se = e;
#pragma unroll
    for (int m = 1; m < 32; m <<= 1) se += __shfl_xor(se, m);
    svals[t] = e * __builtin_amdgcn_rcpf(se);
  }
  __syncthreads();
  float wv[2][4];
#pragma unroll
  for (int mi = 0; mi < 2; ++mi)
#pragma unroll
    for (int r = 0; r < 4; ++r) wv[mi][r] = svals[mi * 16 + rq * 4 + r];

  // ---- pooled + LN2 + scores ----
  float pol[12];
#pragma unroll
  for (int nj = 0; nj < 12; ++nj) {
    float s = 0.f;
#pragma unroll
    for (int mi = 0; mi < 2; ++mi)
#pragma unroll
      for (int r = 0; r < 4; ++r) s += wv[mi][r] * acc[mi][nj][r];
    pol[nj] = s;
  }
#pragma unroll
  for (int nj = 0; nj < 12; ++nj) {
    pol[nj] += __shfl_xor(pol[nj], 16);
    pol[nj] += __shfl_xor(pol[nj], 32);
  }
  float ps = 0.f, pq = 0.f;
#pragma unroll
  for (int nj = 0; nj < 12; ++nj) { ps += pol[nj]; pq += pol[nj] * pol[nj]; }
#pragma unroll
  for (int m = 1; m < 64; m <<= 1) { ps += __shfl_xor(ps, m); pq += __shfl_xor(pq, m); }
  if (l == 0) { red2[w][0] = ps; red2[w][1] = pq; }
  __syncthreads();
  {
    float s = red2[0][0] + red2[1][0] + red2[2][0] + red2[3][0];
    float q2 = red2[0][1] + red2[1][1] + red2[2][1] + red2[3][1];
    const float inv = 1.0f / (4.0f * 768.0f);   // x4 rq replication
    float m2 = s * inv;
    float var2 = q2 * inv - m2 * m2;
    float rs2 = rsqrtf(var2 + 1e-5f);

    const float* ea = entity_cls + (size_t)a * 768;
    const float* mb = mention_cls + (size_t)b * 768;
    const float* ec = ecls + (size_t)a * 768;
    float tot = 0.f;
#pragma unroll
    for (int nj = 0; nj < 12; ++nj) {
      int h = w * 192 + nj * 16 + cg;
      float ctx = (pol[nj] - m2) * rs2 * ln2_g[h] + ln2_b[h];
      tot += ctx * ec[h] + mb[h] * ea[h];
    }
#pragma unroll
    for (int m = 1; m < 64; m <<= 1) tot += __shfl_xor(tot, m);
    if (l == 0) red3[w] = tot;
  }
  __syncthreads();
  if (t == 0) {
    float g = red3[0] + red3[1] + red3[2] + red3[3];
    out[b * 32 + a] = 0.5f * 0.25f * g;
  }
}

extern "C" void kernel_launch(void* const* d_in, const int* in_sizes, int n_in,
                              void* d_out, int out_size, void* d_ws, size_t ws_size,
                              hipStream_t stream) {
  const float* entity_cls     = (const float*)d_in[0];
  const float* entity_tokens  = (const float*)d_in[1];
  const float* mention_cls    = (const float*)d_in[2];
  const float* mention_tokens = (const float*)d_in[3];
  const float* Wq = (const float*)d_in[4];   const float* bq = (const float*)d_in[5];
  const float* Wk = (const float*)d_in[6];   const float* bk = (const float*)d_in[7];
  const float* Wv = (const float*)d_in[8];   const float* bv = (const float*)d_in[9];
  const float* ln1_g = (const float*)d_in[10]; const float* ln1_b = (const float*)d_in[11];
  const float* Wcls = (const float*)d_in[12];  const float* bcls = (const float*)d_in[13];
  const float* Wsp = (const float*)d_in[14];   const float* bsp = (const float*)d_in[15];
  const float* ln2_g = (const float*)d_in[16]; const float* ln2_b = (const float*)d_in[17];
  float* out = (float*)d_out;

  // workspace layout
  float* ws    = (float*)d_ws;
  float* ecls  = ws;                         // 32*768
  float* iq_sq = ecls + 24576;               // 1024
  float* ik_sq = iq_sq + 1024;               // 2048  (contiguous with iq_sq for zeroing)
  unsigned short* qb = (unsigned short*)(ik_sq + 2048);  // 1024*768
  unsigned short* qT = qb + 786432;                      // 32*768*32
  unsigned short* kb = qT + 786432;                      // 2048*768
  unsigned short* vT = kb + 1572864;                     // 64*768*32
  char* R = (char*)(vT + 1572864);
  unsigned short* Ae    = (unsigned short*)R;            // staging (aliased later by Tg)
  unsigned short* Am    = Ae + 786432;
  unsigned short* Acls  = Am + 1572864;
  unsigned short* WqT   = Acls + 24576;
  unsigned short* WkT   = WqT + 589824;
  unsigned short* WvT   = WkT + 589824;
  unsigned short* WclsT = WvT + 589824;
  unsigned short* Tg = (unsigned short*)R;               // 2048*1024 bf16 (4 MB, aliases staging)

  dim3 blk(256);
  prep_kernel<<<dim3(4635), blk, 0, stream>>>(
      entity_tokens, mention_tokens, entity_cls, Ae, Am, Acls, iq_sq,
      Wq, Wk, Wv, Wcls, WqT, WkT, WvT, WclsT);
  proj_gemm_kernel<<<dim3(6, 16, 4), blk, 0, stream>>>(
      Ae, Am, Acls, WqT, WkT, WvT, WclsT, bq, bk, bv, bcls,
      qb, qT, kb, vT, ecls, iq_sq, ik_sq);
  cos_sink_kernel<<<dim3(32, 8), blk, 0, stream>>>(qb, kb, iq_sq, ik_sq, Tg);
  attn_kernel<<<dim3(2048), blk, 0, stream>>>(
      Tg, vT, qT, ecls, entity_cls, mention_cls,
      ln1_g, ln1_b, Wsp, bsp, ln2_g, ln2_b, out);
}